// Round 2
// baseline (76.277 us; speedup 1.0000x reference)
//
#include <hip/hip_runtime.h>

#define MU_F    136.72353790613718f
#define SIGMA_F 62.34640414043511f

// One block per sample j. Computes loss_j into ws[j].
__global__ __launch_bounds__(256) void triplet_per_row(
    const float* __restrict__ feats,
    const float* __restrict__ label,
    const int*   __restrict__ idx1,
    const int*   __restrict__ idx2,
    float* __restrict__ ws,
    int B, int D)
{
    const int j = blockIdx.x;

    // --- replicate _fix_indices exactly ---
    const int r1 = idx1[j] % (B - 1);
    int aIdx = j + 1 + r1; if (aIdx >= B) aIdx -= B;          // a != j
    const int r2 = idx2[j] % (B - 1);
    int bIdx = j + 1 + r2; if (bIdx >= B) bIdx -= B;          // b != j
    if (bIdx == aIdx) {
        const int r2b = (idx2[j] + 1) % (B - 1);
        bIdx = j + 1 + r2b; if (bIdx >= B) bIdx -= B;         // b != a
    }

    // --- label values as the scan would see them (indices < j already normalized) ---
    const float lj = label[j];                                 // never pre-normalized at step j
    float la = label[aIdx]; if (aIdx < j) la = (la - MU_F) / SIGMA_F;
    float lb = label[bIdx]; if (bIdx < j) lb = (lb - MU_F) / SIGMA_F;

    const float* __restrict__ fj = feats + (size_t)j    * (size_t)D;
    const float* __restrict__ fa = feats + (size_t)aIdx * (size_t)D;
    const float* __restrict__ fb = feats + (size_t)bIdx * (size_t)D;

    // --- row distance partials: da = sum((fj-fa)^2), db = sum((fj-fb)^2) ---
    float pa = 0.f, pb = 0.f;
    const int t = threadIdx.x;
    for (int k = t * 8; k < D; k += 256 * 8) {                 // single iter at D=2048
        const float4 x0 = *(const float4*)(fj + k);
        const float4 x1 = *(const float4*)(fj + k + 4);
        const float4 a0 = *(const float4*)(fa + k);
        const float4 a1 = *(const float4*)(fa + k + 4);
        const float4 b0 = *(const float4*)(fb + k);
        const float4 b1 = *(const float4*)(fb + k + 4);
        float d;
        d = x0.x - a0.x; pa += d * d;   d = x0.y - a0.y; pa += d * d;
        d = x0.z - a0.z; pa += d * d;   d = x0.w - a0.w; pa += d * d;
        d = x1.x - a1.x; pa += d * d;   d = x1.y - a1.y; pa += d * d;
        d = x1.z - a1.z; pa += d * d;   d = x1.w - a1.w; pa += d * d;
        d = x0.x - b0.x; pb += d * d;   d = x0.y - b0.y; pb += d * d;
        d = x0.z - b0.z; pb += d * d;   d = x0.w - b0.w; pb += d * d;
        d = x1.x - b1.x; pb += d * d;   d = x1.y - b1.y; pb += d * d;
        d = x1.z - b1.z; pb += d * d;   d = x1.w - b1.w; pb += d * d;
    }

    // wave (64-lane) shuffle reduce, then cross-wave via LDS
    #pragma unroll
    for (int off = 32; off > 0; off >>= 1) {
        pa += __shfl_down(pa, off);
        pb += __shfl_down(pb, off);
    }
    __shared__ float sa[4], sb[4];
    const int wid = t >> 6, lane = t & 63;
    if (lane == 0) { sa[wid] = pa; sb[wid] = pb; }
    __syncthreads();

    if (t == 0) {
        const float da = sa[0] + sa[1] + sa[2] + sa[3];
        const float db = sb[0] + sb[1] + sb[2] + sb[3];

        const float ld1 = fabsf(lj - la);
        const float ld2 = fabsf(lj - lb);
        const bool cond = (ld1 >= ld2);

        const float near_l = cond ? lb : la;
        const float far_l  = cond ? la : lb;
        const float dp     = cond ? db : da;
        const float dn     = cond ? da : db;

        const float li = (lj     - MU_F) / SIGMA_F;
        const float nl = (near_l - MU_F) / SIGMA_F;   // may double-normalize: matches reference
        const float fl = (far_l  - MU_F) / SIGMA_F;

        const float alpha = (li - fl) * (li - fl) - (li - nl) * (li - nl);
        const float loss  = dp - dn + 0.5f * alpha;
        ws[j] = loss > 0.f ? loss : 0.f;
    }
}

// Deterministic single-block reduction of B partials into out[0].
__global__ __launch_bounds__(256) void reduce_losses(
    const float* __restrict__ ws, float* __restrict__ out, int n)
{
    float s = 0.f;
    for (int k = threadIdx.x; k < n; k += 256) s += ws[k];
    #pragma unroll
    for (int off = 32; off > 0; off >>= 1) s += __shfl_down(s, off);
    __shared__ float sm[4];
    const int wid = threadIdx.x >> 6, lane = threadIdx.x & 63;
    if (lane == 0) sm[wid] = s;
    __syncthreads();
    if (threadIdx.x == 0) out[0] = sm[0] + sm[1] + sm[2] + sm[3];
}

extern "C" void kernel_launch(void* const* d_in, const int* in_sizes, int n_in,
                              void* d_out, int out_size, void* d_ws, size_t ws_size,
                              hipStream_t stream)
{
    const float* feats = (const float*)d_in[0];
    const float* label = (const float*)d_in[1];
    const int*   idx1  = (const int*)d_in[2];
    const int*   idx2  = (const int*)d_in[3];

    const int B = in_sizes[1];             // 16384
    const int D = in_sizes[0] / B;         // 2048

    float* ws = (float*)d_ws;              // B floats of scratch

    triplet_per_row<<<B, 256, 0, stream>>>(feats, label, idx1, idx2, ws, B, D);
    reduce_losses<<<1, 256, 0, stream>>>(ws, (float*)d_out, B);
}

// Round 3
// 65.890 us; speedup vs baseline: 1.1576x; 1.1576x over previous
//
#include <hip/hip_runtime.h>

#define MU_F    136.72353790613718f
#define SIGMA_F 62.34640414043511f

// One WAVE (64 lanes) per sample j; 4 rows per 256-thread block.
// Wave-local reduce only: no LDS, no __syncthreads.
__global__ __launch_bounds__(256) void triplet_wave_per_row(
    const float* __restrict__ feats,
    const float* __restrict__ label,
    const int*   __restrict__ idx1,
    const int*   __restrict__ idx2,
    float* __restrict__ ws,
    int B, int D)
{
    const int wid  = threadIdx.x >> 6;
    const int lane = threadIdx.x & 63;
    const int j    = blockIdx.x * 4 + wid;
    if (j >= B) return;

    // --- replicate _fix_indices exactly ---
    const int r1 = idx1[j] % (B - 1);
    int aIdx = j + 1 + r1; if (aIdx >= B) aIdx -= B;          // a != j
    const int r2 = idx2[j] % (B - 1);
    int bIdx = j + 1 + r2; if (bIdx >= B) bIdx -= B;          // b != j
    if (bIdx == aIdx) {
        const int r2b = (idx2[j] + 1) % (B - 1);
        bIdx = j + 1 + r2b; if (bIdx >= B) bIdx -= B;         // b != a
    }

    // --- label values as the sequential scan would see them ---
    const float lj = label[j];
    float la = label[aIdx]; if (aIdx < j) la = (la - MU_F) / SIGMA_F;
    float lb = label[bIdx]; if (bIdx < j) lb = (lb - MU_F) / SIGMA_F;

    const float* __restrict__ fj = feats + (size_t)j    * (size_t)D;
    const float* __restrict__ fa = feats + (size_t)aIdx * (size_t)D;
    const float* __restrict__ fb = feats + (size_t)bIdx * (size_t)D;

    // --- row distance partials: 8 float4 per row per lane at D=2048 ---
    float pa = 0.f, pb = 0.f;
    #pragma unroll 4
    for (int k = lane * 4; k < D; k += 64 * 4) {
        const float4 x = *(const float4*)(fj + k);
        const float4 a = *(const float4*)(fa + k);
        const float4 b = *(const float4*)(fb + k);
        float d;
        d = x.x - a.x; pa += d * d;   d = x.y - a.y; pa += d * d;
        d = x.z - a.z; pa += d * d;   d = x.w - a.w; pa += d * d;
        d = x.x - b.x; pb += d * d;   d = x.y - b.y; pb += d * d;
        d = x.z - b.z; pb += d * d;   d = x.w - b.w; pb += d * d;
    }

    // wave-local butterfly reduce (64 lanes)
    #pragma unroll
    for (int off = 32; off > 0; off >>= 1) {
        pa += __shfl_down(pa, off);
        pb += __shfl_down(pb, off);
    }

    if (lane == 0) {
        const float da = pa, db = pb;

        const float ld1 = fabsf(lj - la);
        const float ld2 = fabsf(lj - lb);
        const bool cond = (ld1 >= ld2);

        const float near_l = cond ? lb : la;
        const float far_l  = cond ? la : lb;
        const float dp     = cond ? db : da;
        const float dn     = cond ? da : db;

        const float li = (lj     - MU_F) / SIGMA_F;
        const float nl = (near_l - MU_F) / SIGMA_F;   // may double-normalize: matches reference
        const float fl = (far_l  - MU_F) / SIGMA_F;

        const float alpha = (li - fl) * (li - fl) - (li - nl) * (li - nl);
        const float loss  = dp - dn + 0.5f * alpha;
        ws[j] = loss > 0.f ? loss : 0.f;
    }
}

// Deterministic single-block reduction of B partials into out[0], float4 loads.
__global__ __launch_bounds__(256) void reduce_losses(
    const float* __restrict__ ws, float* __restrict__ out, int n)
{
    float s = 0.f;
    for (int k = threadIdx.x * 4; k < n; k += 256 * 4) {
        const float4 v = *(const float4*)(ws + k);
        s += (v.x + v.y) + (v.z + v.w);
    }
    #pragma unroll
    for (int off = 32; off > 0; off >>= 1) s += __shfl_down(s, off);
    __shared__ float sm[4];
    const int wid = threadIdx.x >> 6, lane = threadIdx.x & 63;
    if (lane == 0) sm[wid] = s;
    __syncthreads();
    if (threadIdx.x == 0) out[0] = sm[0] + sm[1] + sm[2] + sm[3];
}

extern "C" void kernel_launch(void* const* d_in, const int* in_sizes, int n_in,
                              void* d_out, int out_size, void* d_ws, size_t ws_size,
                              hipStream_t stream)
{
    const float* feats = (const float*)d_in[0];
    const float* label = (const float*)d_in[1];
    const int*   idx1  = (const int*)d_in[2];
    const int*   idx2  = (const int*)d_in[3];

    const int B = in_sizes[1];             // 16384
    const int D = in_sizes[0] / B;         // 2048

    float* ws = (float*)d_ws;              // B floats of scratch

    triplet_wave_per_row<<<(B + 3) / 4, 256, 0, stream>>>(feats, label, idx1, idx2, ws, B, D);
    reduce_losses<<<1, 256, 0, stream>>>(ws, (float*)d_out, B);
}